// Round 1
// baseline (395.872 us; speedup 1.0000x reference)
//
#include <hip/hip_runtime.h>

// ScaledConvolutionalDotProduct: B=4, S=2048, D=1024
//   qp = relu(q@Wq + bq); kp = relu(k@Wk + bk); vp = relu(v@Wv + bv)
//   logits = relu(qp@kp^T)/32 + mask;  out = relu(logits@vp)
// Strategy: bf16 MFMA GEMMs (m97-structure 128x128 tile, global_load_lds w=16).

#define B_ 4
#define S_ 2048
#define D_ 1024

typedef __attribute__((ext_vector_type(8))) short short8;
typedef __attribute__((ext_vector_type(4))) float f32x4;

typedef const __attribute__((address_space(1))) void* gas1;
typedef __attribute__((address_space(3))) void* las3;

static __device__ __forceinline__ short f2bf(float x) {
    union { float f; unsigned u; } un; un.f = x;
    unsigned r = un.u + 0x7fff + ((un.u >> 16) & 1);
    return (short)(r >> 16);
}

// ---------------- fp32 -> bf16 convert (8 elems/thread) ----------------
__global__ void cvt_bf16_kernel(const float* __restrict__ in, short* __restrict__ out) {
    size_t i = ((size_t)blockIdx.x * blockDim.x + threadIdx.x) * 8;
    float4 a = *(const float4*)(in + i);
    float4 b = *(const float4*)(in + i + 4);
    short8 o;
    o[0] = f2bf(a.x); o[1] = f2bf(a.y); o[2] = f2bf(a.z); o[3] = f2bf(a.w);
    o[4] = f2bf(b.x); o[5] = f2bf(b.y); o[6] = f2bf(b.z); o[7] = f2bf(b.w);
    *(short8*)(out + i) = o;
}

// ---------------- W [d][e] fp32 -> W^T [e][d] bf16 ----------------
__global__ void make_wT_kernel(const float* __restrict__ Wq, const float* __restrict__ Wk,
                               const float* __restrict__ Wv, short* __restrict__ wT) {
    const float* W = (blockIdx.z == 0) ? Wq : ((blockIdx.z == 1) ? Wk : Wv);
    short* o = wT + (size_t)blockIdx.z * D_ * D_;
    __shared__ float t[32][33];
    int bx = blockIdx.x, by = blockIdx.y;
    int tx = threadIdx.x & 31, ty = threadIdx.x >> 5;   // 32 x 8
    #pragma unroll
    for (int r = ty; r < 32; r += 8)
        t[r][tx] = W[(size_t)(by * 32 + r) * D_ + bx * 32 + tx];
    __syncthreads();
    #pragma unroll
    for (int r = ty; r < 32; r += 8)
        o[(size_t)(bx * 32 + r) * D_ + by * 32 + tx] = f2bf(t[tx][r]);
}

// ---------------- vp [b][s][e] -> vpT [b][e][s] (bf16) ----------------
__global__ void transpose_bf16_kernel(const short* __restrict__ in, short* __restrict__ out) {
    __shared__ short t[64][65];
    int b = blockIdx.z;
    int e0 = blockIdx.x * 64, s0 = blockIdx.y * 64;
    const short* src = in + (size_t)b * S_ * D_;
    short* dst = out + (size_t)b * D_ * S_;
    int tx = threadIdx.x & 63, ty = threadIdx.x >> 6;   // 64 x 4
    #pragma unroll
    for (int r = ty; r < 64; r += 4)
        t[r][tx] = src[(size_t)(s0 + r) * D_ + e0 + tx];
    __syncthreads();
    #pragma unroll
    for (int r = ty; r < 64; r += 4)
        dst[(size_t)(e0 + r) * S_ + s0 + tx] = t[tx][r];
}

// ---------------- GEMM: C = epilogue(A * B^T)  (A:[M,K], B:[N,K], bf16) ----------------
// EPI 0: bf16 out = relu(acc + bias[n])         (projections)
// EPI 1: bf16 out = relu(acc)*1/32 + mask[m][n] (scores)
// EPI 2: f32  out = relu(acc)                   (PV)
template <int EPI>
__global__ __launch_bounds__(256)
void gemm_bt_kernel(const short* __restrict__ A, const short* __restrict__ B,
                    void* __restrict__ Cv, int M, int N, int K,
                    int lda, int ldb, int ldc,
                    size_t strideA, size_t strideB, size_t strideC,
                    const float* __restrict__ bias, const float* __restrict__ mask, int ldmask) {
    const int tid = threadIdx.x;
    const int lane = tid & 63;
    const int w = tid >> 6;           // wave 0..3
    const int wrow = w >> 1, wcol = w & 1;
    const int bz = blockIdx.z;
    A += (size_t)bz * strideA;
    B += (size_t)bz * strideB;

    const int m0 = blockIdx.x * 128;
    const int n0 = blockIdx.y * 128;

    __shared__ short As[128 * 32];
    __shared__ short Bs[128 * 32];

    f32x4 acc[4][4] = {};

    const int lr = lane & 15;         // row/col within 16x16 fragment
    const int kq = lane >> 4;         // 0..3
    const int klo = kq * 8;           // k offset within 32

    for (int k0 = 0; k0 < K; k0 += 32) {
        // stage 128x32 A-tile and B-tile via global_load_lds (16B/lane)
        #pragma unroll
        for (int i = 0; i < 2; ++i) {
            int chunk = i * 4 + w;          // 0..7, each = 512 elems = 16 rows
            int L = chunk * 512 + lane * 8;
            int r = L >> 5;
            int c = L & 31;
            const short* ga = A + (size_t)(m0 + r) * lda + k0 + c;
            const short* gb = B + (size_t)(n0 + r) * ldb + k0 + c;
            __builtin_amdgcn_global_load_lds((gas1)ga, (las3)(As + chunk * 512), 16, 0, 0);
            __builtin_amdgcn_global_load_lds((gas1)gb, (las3)(Bs + chunk * 512), 16, 0, 0);
        }
        __syncthreads();

        short8 af[4], bfr[4];
        #pragma unroll
        for (int mi = 0; mi < 4; ++mi)
            af[mi] = *(const short8*)&As[(wrow * 64 + mi * 16 + lr) * 32 + klo];
        #pragma unroll
        for (int ni = 0; ni < 4; ++ni)
            bfr[ni] = *(const short8*)&Bs[(wcol * 64 + ni * 16 + lr) * 32 + klo];
        #pragma unroll
        for (int mi = 0; mi < 4; ++mi)
            #pragma unroll
            for (int ni = 0; ni < 4; ++ni)
                acc[mi][ni] = __builtin_amdgcn_mfma_f32_16x16x32_bf16(af[mi], bfr[ni], acc[mi][ni], 0, 0, 0);
        __syncthreads();
    }

    // epilogue: C/D layout col=lane&15, row=(lane>>4)*4+j  [m89-verified]
    short* Cs = (short*)Cv + (size_t)bz * strideC;
    float* Cf = (float*)Cv + (size_t)bz * strideC;
    #pragma unroll
    for (int mi = 0; mi < 4; ++mi) {
        #pragma unroll
        for (int ni = 0; ni < 4; ++ni) {
            int n = n0 + wcol * 64 + ni * 16 + lr;
            int mbase = m0 + wrow * 64 + mi * 16 + kq * 4;
            #pragma unroll
            for (int j = 0; j < 4; ++j) {
                int m = mbase + j;
                float val = acc[mi][ni][j];
                if (EPI == 0) {
                    val = fmaxf(val + bias[n], 0.f);
                    Cs[(size_t)m * ldc + n] = f2bf(val);
                } else if (EPI == 1) {
                    val = fmaxf(val, 0.f) * 0.03125f + mask[(size_t)m * ldmask + n];
                    Cs[(size_t)m * ldc + n] = f2bf(val);
                } else {
                    Cf[(size_t)m * ldc + n] = fmaxf(val, 0.f);
                }
            }
        }
    }
}

extern "C" void kernel_launch(void* const* d_in, const int* in_sizes, int n_in,
                              void* d_out, int out_size, void* d_ws, size_t ws_size,
                              hipStream_t stream) {
    const float* q    = (const float*)d_in[0];
    const float* k    = (const float*)d_in[1];
    const float* v    = (const float*)d_in[2];
    const float* mask = (const float*)d_in[3];
    const float* Wq   = (const float*)d_in[4];
    const float* Wk   = (const float*)d_in[5];
    const float* Wv   = (const float*)d_in[6];
    const float* bq   = (const float*)d_in[7];
    const float* bk   = (const float*)d_in[8];
    const float* bv   = (const float*)d_in[9];
    float* out = (float*)d_out;

    char* ws = (char*)d_ws;
    // layout (bytes):
    //   wT   @ 0         : 3 * 1024*1024*2 = 6,291,456
    //   qp   @ 6,291,456 : 16,777,216
    //   kp   @ 23,068,672: 16,777,216
    //   vpT  @ 39,845,888: 16,777,216
    //   inbf @ 56,623,104: 16,777,216   (dead after projections)
    //   vp   @ 73,400,320: 16,777,216   (dead after transpose)
    //   logits @ 56,623,104: 33,554,432 (overlays inbf+vp)  -> total 90,177,536 B
    short* wT     = (short*)(ws);
    short* qp     = (short*)(ws + 6291456);
    short* kp     = (short*)(ws + 23068672);
    short* vpT    = (short*)(ws + 39845888);
    short* inbf   = (short*)(ws + 56623104);
    short* vp     = (short*)(ws + 73400320);
    short* logits = (short*)(ws + 56623104);

    const int MS = B_ * S_;           // 8192 tokens
    const size_t tok_elems = (size_t)MS * D_;   // 8,388,608

    // 1) W -> W^T bf16 (all three)
    make_wT_kernel<<<dim3(32, 32, 3), 256, 0, stream>>>(Wq, Wk, Wv, wT);

    // 2) projections (convert input to bf16, then gemm_bt against W^T)
    dim3 gproj(MS / 128, D_ / 128, 1);
    cvt_bf16_kernel<<<tok_elems / 8 / 256, 256, 0, stream>>>(q, inbf);
    gemm_bt_kernel<0><<<gproj, 256, 0, stream>>>(inbf, wT, qp, MS, D_, D_,
        D_, D_, D_, 0, 0, 0, bq, nullptr, 0);
    cvt_bf16_kernel<<<tok_elems / 8 / 256, 256, 0, stream>>>(k, inbf);
    gemm_bt_kernel<0><<<gproj, 256, 0, stream>>>(inbf, wT + (size_t)D_ * D_, kp, MS, D_, D_,
        D_, D_, D_, 0, 0, 0, bk, nullptr, 0);
    cvt_bf16_kernel<<<tok_elems / 8 / 256, 256, 0, stream>>>(v, inbf);
    gemm_bt_kernel<0><<<gproj, 256, 0, stream>>>(inbf, wT + 2 * (size_t)D_ * D_, vp, MS, D_, D_,
        D_, D_, D_, 0, 0, 0, bv, nullptr, 0);

    // 3) vp -> vpT per batch
    transpose_bf16_kernel<<<dim3(D_ / 64, S_ / 64, B_), 256, 0, stream>>>(vp, vpT);

    // 4) scores: logits = relu(qp@kp^T)/32 + mask   (bf16, per batch)
    gemm_bt_kernel<1><<<dim3(S_ / 128, S_ / 128, B_), 256, 0, stream>>>(
        qp, kp, logits, S_, S_, D_,
        D_, D_, S_, (size_t)S_ * D_, (size_t)S_ * D_, (size_t)S_ * S_,
        nullptr, mask, S_);

    // 5) PV: out = relu(logits @ vp) = relu(logits @ (vpT)^T)   (f32 out)
    gemm_bt_kernel<2><<<dim3(S_ / 128, D_ / 128, B_), 256, 0, stream>>>(
        logits, vpT, out, S_, D_, S_,
        S_, S_, D_, (size_t)S_ * S_, (size_t)D_ * S_, (size_t)S_ * D_,
        nullptr, nullptr, 0);
}

// Round 2
// 359.291 us; speedup vs baseline: 1.1018x; 1.1018x over previous
//
#include <hip/hip_runtime.h>

// ScaledConvolutionalDotProduct: B=4, S=2048, D=1024
//   qp = relu(q@Wq + bq); kp = relu(k@Wk + bk); vp = relu(v@Wv + bv)
//   logits = relu(qp@kp^T)/32 + mask;  out = relu(logits@vp)
// Round 2: 256-wide 8-phase GEMM (T2 swizzle + T3/T4 counted vmcnt + T5 setprio + T1 XCD swizzle)

#define B_ 4
#define S_ 2048
#define D_ 1024

typedef __attribute__((ext_vector_type(8))) short short8;
typedef __attribute__((ext_vector_type(4))) float f32x4;
typedef const __attribute__((address_space(1))) void* gas1;
typedef __attribute__((address_space(3))) void* las3;

template <int V> struct IC { static constexpr int value = V; };

static __device__ __forceinline__ short f2bf(float x) {
    union { float f; unsigned u; } un; un.f = x;
    unsigned r = un.u + 0x7fff + ((un.u >> 16) & 1);
    return (short)(r >> 16);
}

// ---------------- fp32 -> bf16 convert, q/k/v fused (8 elems/thread) ----------------
__global__ void cvt3_kernel(const float* __restrict__ q, const float* __restrict__ k,
                            const float* __restrict__ v, short* __restrict__ out) {
    const float* in = (blockIdx.y == 0) ? q : ((blockIdx.y == 1) ? k : v);
    size_t i = ((size_t)blockIdx.x * blockDim.x + threadIdx.x) * 8;
    short* o = out + (size_t)blockIdx.y * ((size_t)B_ * S_ * D_);
    float4 a = *(const float4*)(in + i);
    float4 b = *(const float4*)(in + i + 4);
    short8 r;
    r[0] = f2bf(a.x); r[1] = f2bf(a.y); r[2] = f2bf(a.z); r[3] = f2bf(a.w);
    r[4] = f2bf(b.x); r[5] = f2bf(b.y); r[6] = f2bf(b.z); r[7] = f2bf(b.w);
    *(short8*)(o + i) = r;
}

// ---------------- W [d][e] fp32 -> W^T [e][d] bf16 ----------------
__global__ void make_wT_kernel(const float* __restrict__ Wq, const float* __restrict__ Wk,
                               const float* __restrict__ Wv, short* __restrict__ wT) {
    const float* W = (blockIdx.z == 0) ? Wq : ((blockIdx.z == 1) ? Wk : Wv);
    short* o = wT + (size_t)blockIdx.z * D_ * D_;
    __shared__ float t[32][33];
    int bx = blockIdx.x, by = blockIdx.y;
    int tx = threadIdx.x & 31, ty = threadIdx.x >> 5;   // 32 x 8
    #pragma unroll
    for (int r = ty; r < 32; r += 8)
        t[r][tx] = W[(size_t)(by * 32 + r) * D_ + bx * 32 + tx];
    __syncthreads();
    #pragma unroll
    for (int r = ty; r < 32; r += 8)
        o[(size_t)(bx * 32 + r) * D_ + by * 32 + tx] = f2bf(t[tx][r]);
}

// ---------------- vp [b][s][e] -> vpT [b][e][s] (bf16) ----------------
__global__ void transpose_bf16_kernel(const short* __restrict__ in, short* __restrict__ out) {
    __shared__ short t[64][65];
    int b = blockIdx.z;
    int e0 = blockIdx.x * 64, s0 = blockIdx.y * 64;
    const short* src = in + (size_t)b * S_ * D_;
    short* dst = out + (size_t)b * D_ * S_;
    int tx = threadIdx.x & 63, ty = threadIdx.x >> 6;   // 64 x 4
    #pragma unroll
    for (int r = ty; r < 64; r += 4)
        t[r][tx] = src[(size_t)(s0 + r) * D_ + e0 + tx];
    __syncthreads();
    #pragma unroll
    for (int r = ty; r < 64; r += 4)
        dst[(size_t)(e0 + r) * S_ + s0 + tx] = t[tx][r];
}

// ---------------- 8-phase GEMM: C = epilogue(A * B^T), A:[M,K] B:[N,K] bf16 ----------------
// 8 waves (2M x 4N), BM=32*M_REP, BN=64*N_REP, BK=64, double-buffered LDS,
// XOR-swizzled LDS (byte ^= (row&7)<<4, both-sides), counted vmcnt, setprio.
// EPI 0: bf16 = relu(acc + bias[n])      (projections; blockIdx.z selects bias)
// EPI 1: bf16 = relu(acc)/32 + mask[m][n] (scores)
// EPI 2: f32  = relu(acc)                (PV)
template <int M_REP, int N_REP, int EPI>
__global__ __launch_bounds__(512, 2)
void gemm8p_kernel(const short* __restrict__ A, const short* __restrict__ B, void* __restrict__ Cv,
                   int K, int lda, int ldb, int ldc,
                   size_t sA, size_t sB, size_t sC,
                   const float* __restrict__ bias0, const float* __restrict__ bias1,
                   const float* __restrict__ bias2,
                   const float* __restrict__ mask, int ldmask) {
    constexpr int BM = 32 * M_REP;           // 256
    constexpr int BN = 64 * N_REP;           // 256 or 128
    constexpr int A_LOADS = BM / 128;        // gl_lds per thread per A half-tile
    constexpr int B_LOADS = BN / 128;
    constexpr int VMN = 2 * B_LOADS;         // counted vmcnt at phases 4, 8

    __shared__ short As[2][BM * 64];
    __shared__ short Bs[2][BN * 64];

    // T1: bijective XCD swizzle on flat block id (nwg % 8 == 0 for all our launches)
    const int gx = gridDim.x, gy = gridDim.y;
    const int nwg = gx * gy * gridDim.z;
    const int flat = blockIdx.x + gx * (blockIdx.y + gy * blockIdx.z);
    const int swz = (flat & 7) * (nwg >> 3) + (flat >> 3);
    const int bx = swz % gx;
    const int rem = swz / gx;
    const int by = rem % gy;
    const int bz = rem / gy;

    const int m0 = bx * BM, n0 = by * BN;
    const short* Ab = A + (size_t)bz * sA;
    const short* Bb = B + (size_t)bz * sB;

    const int tid = threadIdx.x;
    const int lane = tid & 63;
    const int w = tid >> 6;                  // wave 0..7
    const int wr = w >> 2, wc = w & 3;       // 2 x 4 wave grid
    const int lr16 = lane & 15, kq = lane >> 4;
    const int NT = K >> 6;                   // K-tiles of 64

    // pre-swizzled global source column (bytes): linear (lane&7)*16 XOR row-swz ((lane>>3)&7)<<4
    const int csrc = (((lane & 7) ^ (lane >> 3)) << 4);

    auto stageA = [&](int par, int half, int kt) {
        if (kt >= NT) return;
        #pragma unroll
        for (int l = 0; l < A_LOADS; ++l) {
            int chunk = w * A_LOADS + l;                       // 1024B chunks (8 rows)
            int row = half * (BM / 2) + chunk * 8 + (lane >> 3);
            const char* src = (const char*)Ab + ((size_t)(m0 + row) * lda + (size_t)kt * 64) * 2 + csrc;
            las3 dst = (las3)((char*)&As[par][0] + half * (BM / 2) * 128 + chunk * 1024);
            __builtin_amdgcn_global_load_lds((gas1)src, dst, 16, 0, 0);
        }
    };
    auto stageB = [&](int par, int half, int kt) {
        if (kt >= NT) return;
        #pragma unroll
        for (int l = 0; l < B_LOADS; ++l) {
            int chunk = w * B_LOADS + l;
            int row = half * (BN / 2) + chunk * 8 + (lane >> 3);
            const char* src = (const char*)Bb + ((size_t)(n0 + row) * ldb + (size_t)kt * 64) * 2 + csrc;
            las3 dst = (las3)((char*)&Bs[par][0] + half * (BN / 2) * 128 + chunk * 1024);
            __builtin_amdgcn_global_load_lds((gas1)src, dst, 16, 0, 0);
        }
    };
    // swizzled ds_read of one 16x32 MFMA fragment
    auto ldA = [&](int par, int m, int ks) -> short8 {
        int row = wr * (BM / 2) + m * 16 + lr16;
        int colb = (ks * 64 + ((lane >> 4) << 4)) ^ ((lane & 7) << 4);
        return *(const short8*)((const char*)&As[par][0] + row * 128 + colb);
    };
    auto ldB = [&](int par, int n, int ks) -> short8 {
        int row = wc * (16 * N_REP) + n * 16 + lr16;
        int colb = (ks * 64 + ((lane >> 4) << 4)) ^ ((lane & 7) << 4);
        return *(const short8*)((const char*)&Bs[par][0] + row * 128 + colb);
    };

    f32x4 acc[M_REP][N_REP] = {};
    short8 bfr[2][N_REP];

    // prologue: A(0), B(0), B(1); allow B(1) in flight
    stageA(0, 0, 0); stageA(0, 1, 0);
    stageB(0, 0, 0); stageB(0, 1, 0);
    stageB(1, 0, 1); stageB(1, 1, 1);
    if constexpr (VMN == 4) asm volatile("s_waitcnt vmcnt(4)" ::: "memory");
    else                    asm volatile("s_waitcnt vmcnt(2)" ::: "memory");
    __builtin_amdgcn_s_barrier();

    auto phase = [&](int par, auto ksC, auto mhC, auto stage, auto vmC) {
        constexpr int ks = decltype(ksC)::value;
        constexpr int mh = decltype(mhC)::value;
        constexpr int vm = decltype(vmC)::value;
        short8 a[M_REP / 2];
        #pragma unroll
        for (int m = 0; m < M_REP / 2; ++m) a[m] = ldA(par, mh * (M_REP / 2) + m, ks);
        if constexpr (mh == 0) {
            #pragma unroll
            for (int n = 0; n < N_REP; ++n) bfr[ks][n] = ldB(par, n, ks);
        }
        stage();
        __builtin_amdgcn_s_barrier();
        asm volatile("s_waitcnt lgkmcnt(0)" ::: "memory");
        __builtin_amdgcn_s_setprio(1);
        #pragma unroll
        for (int m = 0; m < M_REP / 2; ++m)
            #pragma unroll
            for (int n = 0; n < N_REP; ++n)
                acc[mh * (M_REP / 2) + m][n] =
                    __builtin_amdgcn_mfma_f32_16x16x32_bf16(a[m], bfr[ks][n],
                                                            acc[mh * (M_REP / 2) + m][n], 0, 0, 0);
        __builtin_amdgcn_s_setprio(0);
        if constexpr (vm) {
            if constexpr (VMN == 4) asm volatile("s_waitcnt vmcnt(4)" ::: "memory");
            else                    asm volatile("s_waitcnt vmcnt(2)" ::: "memory");
        }
        __builtin_amdgcn_s_barrier();
    };

    #pragma unroll 1
    for (int I = 0; I < (NT >> 1); ++I) {
        const int t1 = 2 * I + 1, t2 = 2 * I + 2, t3 = 2 * I + 3;
        phase(0, IC<0>{}, IC<0>{}, [&] { stageA(1, 0, t1); }, IC<0>{});
        phase(0, IC<1>{}, IC<0>{}, [&] { stageA(1, 1, t1); }, IC<0>{});
        phase(0, IC<0>{}, IC<1>{}, [&] { stageB(0, 0, t2); }, IC<0>{});
        phase(0, IC<1>{}, IC<1>{}, [&] { stageB(0, 1, t2); }, IC<1>{});
        phase(1, IC<0>{}, IC<0>{}, [&] { stageA(0, 0, t2); }, IC<0>{});
        phase(1, IC<1>{}, IC<0>{}, [&] { stageA(0, 1, t2); }, IC<0>{});
        phase(1, IC<0>{}, IC<1>{}, [&] { stageB(1, 0, t3); }, IC<0>{});
        phase(1, IC<1>{}, IC<1>{}, [&] { stageB(1, 1, t3); }, IC<1>{});
    }
    asm volatile("s_waitcnt vmcnt(0)" ::: "memory");  // drain before LDS dealloc at wave exit

    // epilogue: C/D layout col=lane&15, row=(lane>>4)*4+j  [m89-verified]
    short* Cs = (short*)Cv + (size_t)bz * sC;
    float* Cf = (float*)Cv + (size_t)bz * sC;
    const float* bias = (EPI == 0) ? ((bz == 0) ? bias0 : ((bz == 1) ? bias1 : bias2)) : nullptr;
    #pragma unroll
    for (int mi = 0; mi < M_REP; ++mi) {
        #pragma unroll
        for (int ni = 0; ni < N_REP; ++ni) {
            int n = n0 + wc * (16 * N_REP) + ni * 16 + lr16;
            int mb = m0 + wr * (BM / 2) + mi * 16 + kq * 4;
            #pragma unroll
            for (int j = 0; j < 4; ++j) {
                int m = mb + j;
                float val = acc[mi][ni][j];
                if constexpr (EPI == 0) {
                    val = fmaxf(val + bias[n], 0.f);
                    Cs[(size_t)m * ldc + n] = f2bf(val);
                } else if constexpr (EPI == 1) {
                    val = fmaxf(val, 0.f) * 0.03125f + mask[(size_t)m * ldmask + n];
                    Cs[(size_t)m * ldc + n] = f2bf(val);
                } else {
                    Cf[(size_t)m * ldc + n] = fmaxf(val, 0.f);
                }
            }
        }
    }
}

extern "C" void kernel_launch(void* const* d_in, const int* in_sizes, int n_in,
                              void* d_out, int out_size, void* d_ws, size_t ws_size,
                              hipStream_t stream) {
    const float* q    = (const float*)d_in[0];
    const float* k    = (const float*)d_in[1];
    const float* v    = (const float*)d_in[2];
    const float* mask = (const float*)d_in[3];
    const float* Wq   = (const float*)d_in[4];
    const float* Wk   = (const float*)d_in[5];
    const float* Wv   = (const float*)d_in[6];
    const float* bq   = (const float*)d_in[7];
    const float* bk   = (const float*)d_in[8];
    const float* bv   = (const float*)d_in[9];
    float* out = (float*)d_out;

    char* ws = (char*)d_ws;
    // layout (bytes):
    //   wT     @ 0          : 3*1024*1024*2   = 6,291,456
    //   qkv_bf @ 6,291,456  : 3*8192*1024*2   = 50,331,648  (dead after projections)
    //   logits @ 6,291,456  : 4*2048*2048*2   = 33,554,432  (overlay on qkv_bf)
    //   qkvp   @ 56,623,104 : 3*8192*1024*2   = 50,331,648  (qp|kp|vp)
    //   vpT    @ 56,623,104 : overlay on qp (qp dead after scores)
    //   total 106,954,752
    short* wT     = (short*)(ws);
    short* qkv_bf = (short*)(ws + 6291456);
    short* logits = (short*)(ws + 6291456);
    short* qkvp   = (short*)(ws + 56623104);
    short* qp     = qkvp;
    short* kp     = qkvp + (size_t)B_ * S_ * D_;
    short* vp     = qkvp + 2 * (size_t)B_ * S_ * D_;
    short* vpT    = qp;   // overlay (qp dead after scores)

    const size_t tok = (size_t)B_ * S_;            // 8192
    const size_t tokD = tok * D_;                  // 8,388,608

    // 1) W -> W^T bf16
    make_wT_kernel<<<dim3(32, 32, 3), 256, 0, stream>>>(Wq, Wk, Wv, wT);

    // 2) q/k/v -> bf16 (one fused launch)
    cvt3_kernel<<<dim3(tokD / 8 / 256, 3), 256, 0, stream>>>(q, k, v, qkv_bf);

    // 3) projections, batched z=3: qp/kp/vp = relu(x @ W + b)   [M=8192,N=1024,K=1024]
    gemm8p_kernel<8, 2, 0><<<dim3(32, 8, 3), 512, 0, stream>>>(
        qkv_bf, wT, qkvp, D_, D_, D_, D_,
        tokD, (size_t)D_ * D_, tokD, bq, bk, bv, nullptr, 0);

    // 4) scores: logits = relu(qp@kp^T)/32 + mask   [per-batch M=N=2048,K=1024]
    gemm8p_kernel<8, 4, 1><<<dim3(8, 8, 4), 512, 0, stream>>>(
        qp, kp, logits, D_, D_, D_, S_,
        (size_t)S_ * D_, (size_t)S_ * D_, (size_t)S_ * S_,
        nullptr, nullptr, nullptr, mask, S_);

    // 5) vp -> vpT per batch (into qp region, dead after scores)
    transpose_bf16_kernel<<<dim3(D_ / 64, S_ / 64, B_), 256, 0, stream>>>(vp, vpT);

    // 6) PV: out = relu(logits @ vpT^T)   [per-batch M=2048,N=1024,K=2048], f32 out
    gemm8p_kernel<8, 2, 2><<<dim3(8, 8, 4), 512, 0, stream>>>(
        logits, vpT, out, S_, S_, S_, D_,
        (size_t)S_ * S_, (size_t)D_ * S_, (size_t)S_ * D_,
        nullptr, nullptr, nullptr, nullptr, 0);
}